// Round 7
// baseline (424.449 us; speedup 1.0000x reference)
//
#include <hip/hip_runtime.h>
#include <cstdint>
#include <cstddef>

// ---------------------------------------------------------------------------
// GraphSAGE 3-layer forward, f32 compute.
//   layer: out = act( mean_gather(h @ W_l) + (h @ W_r + b) )   (linearity swap)
// R7: GEMM restructured. R6 counters: each of 4 col-blocks re-read all of h
// (FETCH 50.5 MB), VALUBusy 59%, LDS pipe ~ VALU pipe -> lgkmcnt stalls.
// Now ONE block does 64 rows x all 2*DOUT cols: 4x(2*DOUT/16) regs/thread,
// BK=32, sH 8KB + sW 8*TOTC KB = 40 KB (DOUT=128) -> 4 blocks/CU.
// Per 4-k chunk: 20 LDS float4 reads vs 256 FMA -> VALU-bound (2.1:1).
// p output stays bf16 (R6 win: halves gather bytes), r stays f32.
// NOTE: harness delivers integer inputs as int32 -> edge_index is const int*.
// ---------------------------------------------------------------------------

#define HID 128
#define SCAN_CHUNK 1024   // deg elements per scan block (256 thr x 4)

// ---- bf16 helpers (manual, RNE) -------------------------------------------

__device__ __forceinline__ unsigned short f32_to_bf16(float f)
{
    union { float f; unsigned int i; } c; c.f = f;
    const unsigned int x = c.i;
    const unsigned int r = x + 0x7fffu + ((x >> 16) & 1u);   // round-nearest-even
    return (unsigned short)(r >> 16);
}

// ---- small utility --------------------------------------------------------

__global__ __launch_bounds__(256) void zero_i32_kernel(int* __restrict__ p, int n)
{
    int i = blockIdx.x * 256 + threadIdx.x;
    if (i < n) p[i] = 0;
}

// ---- CSR build ------------------------------------------------------------

__global__ __launch_bounds__(256) void deg_hist_kernel(
    const int* __restrict__ dst, int* __restrict__ deg, int E, int n)
{
    int e = blockIdx.x * 256 + threadIdx.x;
    if (e < E) {
        int d = dst[e];
        if (d >= 0 && d < n) atomicAdd(&deg[d], 1);
    }
}

__global__ __launch_bounds__(256) void block_sum_kernel(
    const int* __restrict__ deg, int* __restrict__ partials, int n)
{
    __shared__ int red[256];
    const int base = blockIdx.x * SCAN_CHUNK;
    const int t = threadIdx.x;
    int s = 0;
#pragma unroll
    for (int j = 0; j < 4; ++j) {
        const int idx = base + t * 4 + j;
        s += (idx < n) ? deg[idx] : 0;
    }
    red[t] = s;
    __syncthreads();
    for (int off = 128; off > 0; off >>= 1) {
        if (t < off) red[t] += red[t + off];
        __syncthreads();
    }
    if (t == 0) partials[blockIdx.x] = red[0];
}

__global__ __launch_bounds__(256) void scan_partials_kernel(
    int* __restrict__ partials, int nblk)
{
    __shared__ int buf[256];
    const int t = threadIdx.x;
    const int v = (t < nblk) ? partials[t] : 0;
    buf[t] = v;
    __syncthreads();
    for (int off = 1; off < 256; off <<= 1) {
        const int u = (t >= off) ? buf[t - off] : 0;
        __syncthreads();
        buf[t] += u;
        __syncthreads();
    }
    if (t < nblk) partials[t] = buf[t] - v;   // exclusive
}

__global__ __launch_bounds__(256) void scan_write_kernel(
    const int* __restrict__ deg, const int* __restrict__ partials,
    int* __restrict__ offs, int* __restrict__ cursor, int n, int E)
{
    __shared__ int buf[256];
    const int base = blockIdx.x * SCAN_CHUNK;
    const int t = threadIdx.x;
    int loc[4];
    int s = 0;
#pragma unroll
    for (int j = 0; j < 4; ++j) {
        const int idx = base + t * 4 + j;
        const int d = (idx < n) ? deg[idx] : 0;
        loc[j] = s;
        s += d;
    }
    buf[t] = s;
    __syncthreads();
    for (int off = 1; off < 256; off <<= 1) {
        const int u = (t >= off) ? buf[t - off] : 0;
        __syncthreads();
        buf[t] += u;
        __syncthreads();
    }
    const int tbase = partials[blockIdx.x] + ((t == 0) ? 0 : buf[t - 1]);
#pragma unroll
    for (int j = 0; j < 4; ++j) {
        const int idx = base + t * 4 + j;
        if (idx < n) {
            const int o = tbase + loc[j];
            offs[idx] = o;
            cursor[idx] = o;
        }
    }
    if (blockIdx.x == 0 && t == 0) offs[n] = E;
}

__global__ __launch_bounds__(256) void csr_fill_kernel(
    const int* __restrict__ src, const int* __restrict__ dst,
    int* __restrict__ cursor, int* __restrict__ esrc, int E, int n)
{
    int e = blockIdx.x * 256 + threadIdx.x;
    if (e < E) {
        int d = dst[e];
        int s = src[e];
        if (d >= 0 && d < n && s >= 0 && s < n) {
            int p = atomicAdd(&cursor[d], 1);
            esrc[p] = s;
        }
    }
}

// ---- Fused dual GEMM: 64 rows x all 2*DOUT cols per block -----------------
// 256 threads, BK=32, K=128 (4 k-iters). Thread (rg=tx>>4, cg=tx&15) owns
// rows rg*4..+3 and cols {q*64 + cg*4 ..+3} for q in 0..NQ-1.
// Quarters 0..NQ/2-1 = Wl -> p (bf16); NQ/2..NQ-1 = Wr (+bias) -> r (f32).

template <int DOUT>
__global__ __launch_bounds__(256) void sage_dual_gemm(
    const float* __restrict__ h,
    const float* __restrict__ Wl, const float* __restrict__ Wr,
    const float* __restrict__ bias,
    unsigned short* __restrict__ p, float* __restrict__ r, int n)
{
    constexpr int K    = HID;
    constexpr int BK   = 32;
    constexpr int TOTC = 2 * DOUT;
    constexpr int NQ   = TOTC / 64;          // 4 (DOUT=128) or 2 (DOUT=64)
    constexpr int WROW = TOTC / 4;           // float4 per sW row
    constexpr int NWJ  = (BK * WROW) / 256;  // sW float4 per thread: 8 or 4

    __shared__ float sH[64 * BK];            // [row][k ^ ((row&7)<<2)]
    __shared__ float sW[BK * TOTC];          // [k][c]

    const int tx   = threadIdx.x;
    const int row0 = blockIdx.x * 64;
    const int cg   = tx & 15;
    const int rg   = tx >> 4;

    float acc[4][NQ][4];
#pragma unroll
    for (int i = 0; i < 4; ++i)
#pragma unroll
        for (int q = 0; q < NQ; ++q)
#pragma unroll
            for (int j = 0; j < 4; ++j) acc[i][q][j] = 0.f;

    for (int kk = 0; kk < K; kk += BK) {
        // stage H: 64 rows x 32 k = 512 float4, 2 per thread, XOR-swizzled
#pragma unroll
        for (int j = 0; j < 2; ++j) {
            const int i  = tx + j * 256;
            const int rw = i >> 3;            // 8 float4 per row
            const int c4 = (i & 7) * 4;
            const int row = row0 + rw;
            float4 v = make_float4(0.f, 0.f, 0.f, 0.f);
            if (row < n) v = *(const float4*)(&h[(size_t)row * K + kk + c4]);
            *(float4*)&sH[rw * BK + (c4 ^ ((rw & 7) << 2))] = v;
        }
        // stage W: 32 k x TOTC cols; col<DOUT from Wl, else Wr
#pragma unroll
        for (int j = 0; j < NWJ; ++j) {
            const int i  = tx + j * 256;
            const int kw = i / WROW;
            const int c4 = (i % WROW) * 4;
            const float4 v = (c4 < DOUT)
                ? *(const float4*)(&Wl[(size_t)(kk + kw) * DOUT + c4])
                : *(const float4*)(&Wr[(size_t)(kk + kw) * DOUT + (c4 - DOUT)]);
            *(float4*)&sW[kw * TOTC + c4] = v;
        }
        __syncthreads();

#pragma unroll
        for (int k0 = 0; k0 < BK; k0 += 4) {
            float4 hv[4];
#pragma unroll
            for (int i = 0; i < 4; ++i) {
                const int rw = rg * 4 + i;
                hv[i] = *(const float4*)&sH[rw * BK + (k0 ^ ((rw & 7) << 2))];
            }
#pragma unroll
            for (int kq = 0; kq < 4; ++kq) {
                float4 wv[NQ];
#pragma unroll
                for (int q = 0; q < NQ; ++q)
                    wv[q] = *(const float4*)&sW[(k0 + kq) * TOTC + q * 64 + cg * 4];
#pragma unroll
                for (int i = 0; i < 4; ++i) {
                    const float hval = (kq == 0) ? hv[i].x : (kq == 1) ? hv[i].y
                                     : (kq == 2) ? hv[i].z : hv[i].w;
#pragma unroll
                    for (int q = 0; q < NQ; ++q) {
                        acc[i][q][0] = fmaf(hval, wv[q].x, acc[i][q][0]);
                        acc[i][q][1] = fmaf(hval, wv[q].y, acc[i][q][1]);
                        acc[i][q][2] = fmaf(hval, wv[q].z, acc[i][q][2]);
                        acc[i][q][3] = fmaf(hval, wv[q].w, acc[i][q][3]);
                    }
                }
            }
        }
        __syncthreads();
    }

    // epilogue: quarters [0, NQ/2) -> p as bf16; [NQ/2, NQ) -> r + bias (f32)
    float4 bv[NQ / 2];
#pragma unroll
    for (int q = 0; q < NQ / 2; ++q)
        bv[q] = *(const float4*)(&bias[q * 64 + cg * 4]);

#pragma unroll
    for (int i = 0; i < 4; ++i) {
        const int row = row0 + rg * 4 + i;
        if (row < n) {
#pragma unroll
            for (int q = 0; q < NQ / 2; ++q) {
                ushort4 o;
                o.x = f32_to_bf16(acc[i][q][0]);
                o.y = f32_to_bf16(acc[i][q][1]);
                o.z = f32_to_bf16(acc[i][q][2]);
                o.w = f32_to_bf16(acc[i][q][3]);
                *(ushort4*)(&p[(size_t)row * DOUT + q * 64 + cg * 4]) = o;
            }
#pragma unroll
            for (int q = 0; q < NQ / 2; ++q) {
                const int qq = q + NQ / 2;
                float4 o;
                o.x = acc[i][qq][0] + bv[q].x;
                o.y = acc[i][qq][1] + bv[q].y;
                o.z = acc[i][qq][2] + bv[q].z;
                o.w = acc[i][qq][3] + bv[q].w;
                *(float4*)(&r[(size_t)row * DOUT + q * 64 + cg * 4]) = o;
            }
        }
    }
}

// ---- Post-aggregation: out = act( mean(p_bf16[nbrs]) + r ) ----------------
// One wave per dst node. Predicated x8 unroll -> 8 gathers in flight.

template <int DOUT, bool RELU>
__global__ __launch_bounds__(256) void sage_post_aggregate(
    const unsigned short* __restrict__ p, const float* __restrict__ r,
    const int* __restrict__ offs, const int* __restrict__ esrc,
    float* __restrict__ out, int n)
{
    const int wid  = threadIdx.x >> 6;
    const int lane = threadIdx.x & 63;
    const int node = blockIdx.x * 4 + wid;
    if (node >= n) return;
    const int beg = offs[node];
    const int end = offs[node + 1];
    const float inv = 1.0f / fmaxf((float)(end - beg), 1.0f);

    if constexpr (DOUT == 128) {
        float ax[8], ay[8];
#pragma unroll
        for (int j = 0; j < 8; ++j) { ax[j] = 0.f; ay[j] = 0.f; }
        for (int e = beg; e < end; e += 8) {
#pragma unroll
            for (int j = 0; j < 8; ++j) {
                const int idx = e + j;
                const int ee  = min(idx, end - 1);
                const float w = (idx < end) ? 1.0f : 0.0f;
                const int s   = esrc[ee];
                const unsigned int v = *(const unsigned int*)(&p[(size_t)s * DOUT + lane * 2]);
                float fx, fy;
                { union { unsigned int i; float f; } c; c.i = v << 16;          fx = c.f; }
                { union { unsigned int i; float f; } c; c.i = v & 0xffff0000u;  fy = c.f; }
                ax[j] = fmaf(w, fx, ax[j]);
                ay[j] = fmaf(w, fy, ay[j]);
            }
        }
        float sx = ((ax[0] + ax[1]) + (ax[2] + ax[3])) + ((ax[4] + ax[5]) + (ax[6] + ax[7]));
        float sy = ((ay[0] + ay[1]) + (ay[2] + ay[3])) + ((ay[4] + ay[5]) + (ay[6] + ay[7]));
        const float2 rv = *(const float2*)(&r[(size_t)node * DOUT + lane * 2]);
        float ox = sx * inv + rv.x;
        float oy = sy * inv + rv.y;
        if (RELU) { ox = fmaxf(ox, 0.f); oy = fmaxf(oy, 0.f); }
        float2 o; o.x = ox; o.y = oy;
        *(float2*)(&out[(size_t)node * DOUT + lane * 2]) = o;
    } else {
        float a[8];
#pragma unroll
        for (int j = 0; j < 8; ++j) a[j] = 0.f;
        for (int e = beg; e < end; e += 8) {
#pragma unroll
            for (int j = 0; j < 8; ++j) {
                const int idx = e + j;
                const int ee  = min(idx, end - 1);
                const float w = (idx < end) ? 1.0f : 0.0f;
                const int s   = esrc[ee];
                const unsigned short u = p[(size_t)s * DOUT + lane];
                union { unsigned int i; float f; } c; c.i = ((unsigned int)u) << 16;
                a[j] = fmaf(w, c.f, a[j]);
            }
        }
        float sa = ((a[0] + a[1]) + (a[2] + a[3])) + ((a[4] + a[5]) + (a[6] + a[7]));
        float o = sa * inv + r[(size_t)node * DOUT + lane];
        if (RELU) o = fmaxf(o, 0.f);
        out[(size_t)node * DOUT + lane] = o;
    }
}

// ---------------------------------------------------------------------------

static inline size_t align_up(size_t v, size_t a) { return (v + a - 1) & ~(a - 1); }

extern "C" void kernel_launch(void* const* d_in, const int* in_sizes, int n_in,
                              void* d_out, int out_size, void* d_ws, size_t ws_size,
                              hipStream_t stream)
{
    const float* x   = (const float*)d_in[0];
    const int*   ei  = (const int*)d_in[1];      // int32! (harness converts int64)
    const float* wl0 = (const float*)d_in[2];
    const float* b0  = (const float*)d_in[3];
    const float* wr0 = (const float*)d_in[4];
    const float* wl1 = (const float*)d_in[5];
    const float* b1  = (const float*)d_in[6];
    const float* wr1 = (const float*)d_in[7];
    const float* wl2 = (const float*)d_in[8];
    const float* b2  = (const float*)d_in[9];
    const float* wr2 = (const float*)d_in[10];
    float*       out = (float*)d_out;

    const int N = in_sizes[0] / HID;   // 50000
    const int E = in_sizes[1] / 2;     // 800000
    const int* src = ei;
    const int* dst = ei + E;

    // Workspace carve-up (~68 MB)
    char*  ws  = (char*)d_ws;
    size_t off = 0;
    int* offs     = (int*)(ws + off); off = align_up(off + (size_t)(N + 1) * 4, 256);
    int* cursor   = (int*)(ws + off); off = align_up(off + (size_t)N * 4, 256);
    int* deg      = (int*)(ws + off); off = align_up(off + (size_t)N * 4, 256);
    int* partials = (int*)(ws + off); off = align_up(off + 256 * 4, 256);
    int* esrc     = (int*)(ws + off); off = align_up(off + (size_t)E * 4, 256);
    unsigned short* pbuf = (unsigned short*)(ws + off); off = align_up(off + (size_t)N * HID * 2, 256);
    float* rbuf   = (float*)(ws + off); off = align_up(off + (size_t)N * HID * 4, 256);
    float* hbuf   = (float*)(ws + off); off = align_up(off + (size_t)N * HID * 4, 256);
    (void)ws_size; (void)n_in; (void)out_size;

    const int nScanBlk = (N + SCAN_CHUNK - 1) / SCAN_CHUNK;   // 49

    // --- CSR build (reused by all 3 layers) ---
    zero_i32_kernel<<<(N + 255) / 256, 256, 0, stream>>>(deg, N);
    deg_hist_kernel<<<(E + 255) / 256, 256, 0, stream>>>(dst, deg, E, N);
    block_sum_kernel<<<nScanBlk, 256, 0, stream>>>(deg, partials, N);
    scan_partials_kernel<<<1, 256, 0, stream>>>(partials, nScanBlk);
    scan_write_kernel<<<nScanBlk, 256, 0, stream>>>(deg, partials, offs, cursor, N, E);
    csr_fill_kernel<<<(E + 255) / 256, 256, 0, stream>>>(src, dst, cursor, esrc, E, N);

    const int aggGrid = (N + 3) / 4;
    const int rowBlk  = (N + 63) / 64;

    // Layer 0: x -> hbuf (ReLU)
    sage_dual_gemm<128><<<rowBlk, 256, 0, stream>>>(x, wl0, wr0, b0, pbuf, rbuf, N);
    sage_post_aggregate<128, true><<<aggGrid, 256, 0, stream>>>(pbuf, rbuf, offs, esrc, hbuf, N);

    // Layer 1: hbuf -> hbuf (ReLU)
    sage_dual_gemm<128><<<rowBlk, 256, 0, stream>>>(hbuf, wl1, wr1, b1, pbuf, rbuf, N);
    sage_post_aggregate<128, true><<<aggGrid, 256, 0, stream>>>(pbuf, rbuf, offs, esrc, hbuf, N);

    // Layer 2: hbuf -> out (no ReLU), 64-wide bf16 gather (128 B/row)
    sage_dual_gemm<64><<<rowBlk, 256, 0, stream>>>(hbuf, wl2, wr2, b2, pbuf, rbuf, N);
    sage_post_aggregate<64, false><<<aggGrid, 256, 0, stream>>>(pbuf, rbuf, offs, esrc, out, N);
}

// Round 8
// 358.739 us; speedup vs baseline: 1.1832x; 1.1832x over previous
//
#include <hip/hip_runtime.h>
#include <cstdint>
#include <cstddef>

// ---------------------------------------------------------------------------
// GraphSAGE 3-layer forward.
//   layer: out = act( mean_gather(h @ W_l) + (h @ W_r + b) )   (linearity swap)
// R8: GEMM on the MFMA pipe (mfma_f32_16x16x32_bf16), B-stationary, LDS-free:
//   - W^T (bf16, [2*DOUT][128], Wl||Wr) prepped per layer (L2-resident 64KB).
//   - each wave owns 64 cols; B-frags live in registers for the whole kernel;
//     grid-stride over 16-row slabs, A-frags loaded straight from global.
//   - no LDS, no barriers -> no R7 occupancy cliff (R7: mega f32 tile died at
//     14% occupancy; f32 vector GEMM capped ~59us/layer).
// h between layers stored bf16 (halves aggregate write + GEMM read).
// p stays bf16 (R6 win), r stays f32. MFMA accum f32.
// MFMA layouts (per guide, m89/m91/m120-verified): A[m=lane&15][k=quad*8+j],
// B[k=quad*8+j][n=lane&15] (from W^T rows), C/D col=lane&15,row=quad*4+reg.
// NOTE: harness delivers integer inputs as int32 -> edge_index is const int*.
// ---------------------------------------------------------------------------

#define HID 128
#define SCAN_CHUNK 1024

using short8 = __attribute__((ext_vector_type(8))) short;
using f32x4  = __attribute__((ext_vector_type(4))) float;

// ---- bf16 helpers (manual, RNE) -------------------------------------------

__device__ __forceinline__ unsigned short f32_to_bf16(float f)
{
    union { float f; unsigned int i; } c; c.f = f;
    const unsigned int x = c.i;
    const unsigned int r = x + 0x7fffu + ((x >> 16) & 1u);
    return (unsigned short)(r >> 16);
}

// ---- small utility --------------------------------------------------------

__global__ __launch_bounds__(256) void zero_i32_kernel(int* __restrict__ p, int n)
{
    int i = blockIdx.x * 256 + threadIdx.x;
    if (i < n) p[i] = 0;
}

// ---- CSR build ------------------------------------------------------------

__global__ __launch_bounds__(256) void deg_hist_kernel(
    const int* __restrict__ dst, int* __restrict__ deg, int E, int n)
{
    int e = blockIdx.x * 256 + threadIdx.x;
    if (e < E) {
        int d = dst[e];
        if (d >= 0 && d < n) atomicAdd(&deg[d], 1);
    }
}

__global__ __launch_bounds__(256) void block_sum_kernel(
    const int* __restrict__ deg, int* __restrict__ partials, int n)
{
    __shared__ int red[256];
    const int base = blockIdx.x * SCAN_CHUNK;
    const int t = threadIdx.x;
    int s = 0;
#pragma unroll
    for (int j = 0; j < 4; ++j) {
        const int idx = base + t * 4 + j;
        s += (idx < n) ? deg[idx] : 0;
    }
    red[t] = s;
    __syncthreads();
    for (int off = 128; off > 0; off >>= 1) {
        if (t < off) red[t] += red[t + off];
        __syncthreads();
    }
    if (t == 0) partials[blockIdx.x] = red[0];
}

__global__ __launch_bounds__(256) void scan_partials_kernel(
    int* __restrict__ partials, int nblk)
{
    __shared__ int buf[256];
    const int t = threadIdx.x;
    const int v = (t < nblk) ? partials[t] : 0;
    buf[t] = v;
    __syncthreads();
    for (int off = 1; off < 256; off <<= 1) {
        const int u = (t >= off) ? buf[t - off] : 0;
        __syncthreads();
        buf[t] += u;
        __syncthreads();
    }
    if (t < nblk) partials[t] = buf[t] - v;   // exclusive
}

__global__ __launch_bounds__(256) void scan_write_kernel(
    const int* __restrict__ deg, const int* __restrict__ partials,
    int* __restrict__ offs, int* __restrict__ cursor, int n, int E)
{
    __shared__ int buf[256];
    const int base = blockIdx.x * SCAN_CHUNK;
    const int t = threadIdx.x;
    int loc[4];
    int s = 0;
#pragma unroll
    for (int j = 0; j < 4; ++j) {
        const int idx = base + t * 4 + j;
        const int d = (idx < n) ? deg[idx] : 0;
        loc[j] = s;
        s += d;
    }
    buf[t] = s;
    __syncthreads();
    for (int off = 1; off < 256; off <<= 1) {
        const int u = (t >= off) ? buf[t - off] : 0;
        __syncthreads();
        buf[t] += u;
        __syncthreads();
    }
    const int tbase = partials[blockIdx.x] + ((t == 0) ? 0 : buf[t - 1]);
#pragma unroll
    for (int j = 0; j < 4; ++j) {
        const int idx = base + t * 4 + j;
        if (idx < n) {
            const int o = tbase + loc[j];
            offs[idx] = o;
            cursor[idx] = o;
        }
    }
    if (blockIdx.x == 0 && t == 0) offs[n] = E;
}

__global__ __launch_bounds__(256) void csr_fill_kernel(
    const int* __restrict__ src, const int* __restrict__ dst,
    int* __restrict__ cursor, int* __restrict__ esrc, int E, int n)
{
    int e = blockIdx.x * 256 + threadIdx.x;
    if (e < E) {
        int d = dst[e];
        int s = src[e];
        if (d >= 0 && d < n && s >= 0 && s < n) {
            int p = atomicAdd(&cursor[d], 1);
            esrc[p] = s;
        }
    }
}

// ---- W^T prep: wtc[c][k] = bf16( c<dout ? Wl[k][c] : Wr[k][c-dout] ) -------

__global__ __launch_bounds__(256) void prep_wt_kernel(
    const float* __restrict__ Wl, const float* __restrict__ Wr,
    unsigned short* __restrict__ wtc, int dout)
{
    const int idx = blockIdx.x * 256 + threadIdx.x;
    const int total = 2 * dout * HID;
    if (idx >= total) return;
    const int k = idx & (HID - 1);
    const int c = idx >> 7;
    const float v = (c < dout) ? Wl[(size_t)k * dout + c]
                               : Wr[(size_t)k * dout + (c - dout)];
    wtc[(size_t)c * HID + k] = f32_to_bf16(v);
}

// ---- MFMA dual GEMM: p = bf16(h@Wl), r = h@Wr + b (f32) -------------------
// 256 thr = 4 waves; wave owns 64 cols (CPW=TOTC/64 tiles of 16); B-frags in
// registers for the whole kernel; grid-stride over 16-row slabs; no LDS.

template <int DOUT, bool IN_F32>
__global__ __launch_bounds__(256) void sage_mfma_gemm(
    const void* __restrict__ hin,                 // [n][128] f32 or bf16
    const unsigned short* __restrict__ wtc,       // [2*DOUT][128] bf16
    const float* __restrict__ bias,
    unsigned short* __restrict__ p, float* __restrict__ r, int n)
{
    constexpr int TOTC = 2 * DOUT;
    constexpr int CPW  = TOTC / 64;   // col-tiles per wave: 4 (DOUT=128) or 2

    const int tx   = threadIdx.x;
    const int wv   = tx >> 6;
    const int lane = tx & 63;
    const int quad = lane >> 4;
    const int l15  = lane & 15;

    // resident B fragments: B[t][q] = W^T[(ct*16+l15)][q*32 + quad*8 .. +7]
    short8 B[CPW][4];
#pragma unroll
    for (int t = 0; t < CPW; ++t) {
        const int c = (wv * CPW + t) * 16 + l15;
#pragma unroll
        for (int q = 0; q < 4; ++q)
            B[t][q] = *(const short8*)(wtc + (size_t)c * HID + q * 32 + quad * 8);
    }

    const int slabs = (n + 15) >> 4;
    for (int slab = blockIdx.x; slab < slabs; slab += gridDim.x) {
        const int r0 = slab * 16;
        const int rr = min(r0 + l15, n - 1);

        short8 A[4];
        if (IN_F32) {
            const float* hf = (const float*)hin;
#pragma unroll
            for (int q = 0; q < 4; ++q) {
                const float* base = hf + (size_t)rr * HID + q * 32 + quad * 8;
                const float4 f0 = *(const float4*)base;
                const float4 f1 = *(const float4*)(base + 4);
                short8 a;
                a[0] = (short)f32_to_bf16(f0.x); a[1] = (short)f32_to_bf16(f0.y);
                a[2] = (short)f32_to_bf16(f0.z); a[3] = (short)f32_to_bf16(f0.w);
                a[4] = (short)f32_to_bf16(f1.x); a[5] = (short)f32_to_bf16(f1.y);
                a[6] = (short)f32_to_bf16(f1.z); a[7] = (short)f32_to_bf16(f1.w);
                A[q] = a;
            }
        } else {
            const unsigned short* hb = (const unsigned short*)hin;
#pragma unroll
            for (int q = 0; q < 4; ++q)
                A[q] = *(const short8*)(hb + (size_t)rr * HID + q * 32 + quad * 8);
        }

        f32x4 acc[CPW];
#pragma unroll
        for (int t = 0; t < CPW; ++t) acc[t] = (f32x4){0.f, 0.f, 0.f, 0.f};
#pragma unroll
        for (int q = 0; q < 4; ++q)
#pragma unroll
            for (int t = 0; t < CPW; ++t)
                acc[t] = __builtin_amdgcn_mfma_f32_16x16x32_bf16(A[q], B[t][q], acc[t], 0, 0, 0);

        // epilogue: C/D layout col=l15, row=quad*4+i
#pragma unroll
        for (int t = 0; t < CPW; ++t) {
            const int c0  = (wv * CPW + t) * 16;
            const int col = c0 + l15;
            if (c0 < DOUT) {
#pragma unroll
                for (int i = 0; i < 4; ++i) {
                    const int row = r0 + quad * 4 + i;
                    if (row < n) p[(size_t)row * DOUT + col] = f32_to_bf16(acc[t][i]);
                }
            } else {
                const float bv = bias[col - DOUT];
#pragma unroll
                for (int i = 0; i < 4; ++i) {
                    const int row = r0 + quad * 4 + i;
                    if (row < n) r[(size_t)row * DOUT + (col - DOUT)] = acc[t][i] + bv;
                }
            }
        }
    }
}

// ---- Post-aggregation: out = act( mean(p_bf16[nbrs]) + r ) ----------------
// One wave per dst node; predicated x8 unroll (8 gathers in flight).
// OUTBF16: write h as packed bf16 (feeds next MFMA GEMM); else f32.

template <int DOUT, bool RELU, bool OUTBF16>
__global__ __launch_bounds__(256) void sage_post_aggregate(
    const unsigned short* __restrict__ p, const float* __restrict__ r,
    const int* __restrict__ offs, const int* __restrict__ esrc,
    void* __restrict__ out, int n)
{
    const int wid  = threadIdx.x >> 6;
    const int lane = threadIdx.x & 63;
    const int node = blockIdx.x * 4 + wid;
    if (node >= n) return;
    const int beg = offs[node];
    const int end = offs[node + 1];
    const float inv = 1.0f / fmaxf((float)(end - beg), 1.0f);

    if constexpr (DOUT == 128) {
        float ax[8], ay[8];
#pragma unroll
        for (int j = 0; j < 8; ++j) { ax[j] = 0.f; ay[j] = 0.f; }
        for (int e = beg; e < end; e += 8) {
#pragma unroll
            for (int j = 0; j < 8; ++j) {
                const int idx = e + j;
                const int ee  = min(idx, end - 1);
                const float w = (idx < end) ? 1.0f : 0.0f;
                const int s   = esrc[ee];
                const unsigned int v = *(const unsigned int*)(&p[(size_t)s * DOUT + lane * 2]);
                float fx, fy;
                { union { unsigned int i; float f; } c; c.i = v << 16;          fx = c.f; }
                { union { unsigned int i; float f; } c; c.i = v & 0xffff0000u;  fy = c.f; }
                ax[j] = fmaf(w, fx, ax[j]);
                ay[j] = fmaf(w, fy, ay[j]);
            }
        }
        float sx = ((ax[0] + ax[1]) + (ax[2] + ax[3])) + ((ax[4] + ax[5]) + (ax[6] + ax[7]));
        float sy = ((ay[0] + ay[1]) + (ay[2] + ay[3])) + ((ay[4] + ay[5]) + (ay[6] + ay[7]));
        const float2 rv = *(const float2*)(&r[(size_t)node * DOUT + lane * 2]);
        float ox = sx * inv + rv.x;
        float oy = sy * inv + rv.y;
        if (RELU) { ox = fmaxf(ox, 0.f); oy = fmaxf(oy, 0.f); }
        if (OUTBF16) {
            const unsigned int pk = ((unsigned int)f32_to_bf16(oy) << 16) | (unsigned int)f32_to_bf16(ox);
            ((unsigned int*)out)[(size_t)node * (DOUT / 2) + lane] = pk;
        } else {
            float2 o; o.x = ox; o.y = oy;
            *(float2*)((float*)out + (size_t)node * DOUT + lane * 2) = o;
        }
    } else {
        float a[8];
#pragma unroll
        for (int j = 0; j < 8; ++j) a[j] = 0.f;
        for (int e = beg; e < end; e += 8) {
#pragma unroll
            for (int j = 0; j < 8; ++j) {
                const int idx = e + j;
                const int ee  = min(idx, end - 1);
                const float w = (idx < end) ? 1.0f : 0.0f;
                const int s   = esrc[ee];
                const unsigned short u = p[(size_t)s * DOUT + lane];
                union { unsigned int i; float f; } c; c.i = ((unsigned int)u) << 16;
                a[j] = fmaf(w, c.f, a[j]);
            }
        }
        float sa = ((a[0] + a[1]) + (a[2] + a[3])) + ((a[4] + a[5]) + (a[6] + a[7]));
        float o = sa * inv + r[(size_t)node * DOUT + lane];
        if (RELU) o = fmaxf(o, 0.f);
        ((float*)out)[(size_t)node * DOUT + lane] = o;
    }
}

// ---------------------------------------------------------------------------

static inline size_t align_up(size_t v, size_t a) { return (v + a - 1) & ~(a - 1); }

extern "C" void kernel_launch(void* const* d_in, const int* in_sizes, int n_in,
                              void* d_out, int out_size, void* d_ws, size_t ws_size,
                              hipStream_t stream)
{
    const float* x   = (const float*)d_in[0];
    const int*   ei  = (const int*)d_in[1];      // int32! (harness converts int64)
    const float* wl0 = (const float*)d_in[2];
    const float* b0  = (const float*)d_in[3];
    const float* wr0 = (const float*)d_in[4];
    const float* wl1 = (const float*)d_in[5];
    const float* b1  = (const float*)d_in[6];
    const float* wr1 = (const float*)d_in[7];
    const float* wl2 = (const float*)d_in[8];
    const float* b2  = (const float*)d_in[9];
    const float* wr2 = (const float*)d_in[10];
    float*       out = (float*)d_out;

    const int N = in_sizes[0] / HID;   // 50000
    const int E = in_sizes[1] / 2;     // 800000
    const int* src = ei;
    const int* dst = ei + E;

    // Workspace carve-up (~55 MB)
    char*  ws  = (char*)d_ws;
    size_t off = 0;
    int* offs     = (int*)(ws + off); off = align_up(off + (size_t)(N + 1) * 4, 256);
    int* cursor   = (int*)(ws + off); off = align_up(off + (size_t)N * 4, 256);
    int* deg      = (int*)(ws + off); off = align_up(off + (size_t)N * 4, 256);
    int* partials = (int*)(ws + off); off = align_up(off + 256 * 4, 256);
    int* esrc     = (int*)(ws + off); off = align_up(off + (size_t)E * 4, 256);
    unsigned short* pbuf = (unsigned short*)(ws + off); off = align_up(off + (size_t)N * HID * 2, 256);
    float* rbuf   = (float*)(ws + off); off = align_up(off + (size_t)N * HID * 4, 256);
    unsigned short* hbf = (unsigned short*)(ws + off); off = align_up(off + (size_t)N * HID * 2, 256);
    unsigned short* wt0 = (unsigned short*)(ws + off); off = align_up(off + (size_t)2 * HID * HID * 2, 256);
    unsigned short* wt1 = (unsigned short*)(ws + off); off = align_up(off + (size_t)2 * HID * HID * 2, 256);
    unsigned short* wt2 = (unsigned short*)(ws + off); off = align_up(off + (size_t)HID * HID * 2, 256);
    (void)ws_size; (void)n_in; (void)out_size;

    const int nScanBlk = (N + SCAN_CHUNK - 1) / SCAN_CHUNK;   // 49

    // --- CSR build (reused by all 3 layers) ---
    zero_i32_kernel<<<(N + 255) / 256, 256, 0, stream>>>(deg, N);
    deg_hist_kernel<<<(E + 255) / 256, 256, 0, stream>>>(dst, deg, E, N);
    block_sum_kernel<<<nScanBlk, 256, 0, stream>>>(deg, partials, N);
    scan_partials_kernel<<<1, 256, 0, stream>>>(partials, nScanBlk);
    scan_write_kernel<<<nScanBlk, 256, 0, stream>>>(deg, partials, offs, cursor, N, E);
    csr_fill_kernel<<<(E + 255) / 256, 256, 0, stream>>>(src, dst, cursor, esrc, E, N);

    // --- W^T preps (bf16) ---
    prep_wt_kernel<<<(2 * HID * HID + 255) / 256, 256, 0, stream>>>(wl0, wr0, wt0, HID);
    prep_wt_kernel<<<(2 * HID * HID + 255) / 256, 256, 0, stream>>>(wl1, wr1, wt1, HID);
    prep_wt_kernel<<<(HID * HID + 255) / 256, 256, 0, stream>>>(wl2, wr2, wt2, 64);

    const int aggGrid  = (N + 3) / 4;
    const int gemmGrid = 1024;   // grid-stride over 3125 slabs

    // Layer 0: x (f32) -> p/r -> hbf (bf16, ReLU)
    sage_mfma_gemm<128, true><<<gemmGrid, 256, 0, stream>>>(x, wt0, b0, pbuf, rbuf, N);
    sage_post_aggregate<128, true, true><<<aggGrid, 256, 0, stream>>>(pbuf, rbuf, offs, esrc, hbf, N);

    // Layer 1: hbf -> p/r -> hbf (bf16, ReLU)
    sage_mfma_gemm<128, false><<<gemmGrid, 256, 0, stream>>>(hbf, wt1, b1, pbuf, rbuf, N);
    sage_post_aggregate<128, true, true><<<aggGrid, 256, 0, stream>>>(pbuf, rbuf, offs, esrc, hbf, N);

    // Layer 2: hbf -> p/r -> out (f32, no ReLU)
    sage_mfma_gemm<64, false><<<gemmGrid, 256, 0, stream>>>(hbf, wt2, b2, pbuf, rbuf, N);
    sage_post_aggregate<64, false, false><<<aggGrid, 256, 0, stream>>>(pbuf, rbuf, offs, esrc, out, N);
}

// Round 9
// 348.786 us; speedup vs baseline: 1.2169x; 1.0285x over previous
//
#include <hip/hip_runtime.h>
#include <cstdint>
#include <cstddef>

// ---------------------------------------------------------------------------
// GraphSAGE 3-layer forward.
//   layer: out = act( mean_gather(h @ W_l) + (h @ W_r + b) )   (linearity swap)
// R8: MFMA GEMM (B-stationary, LDS-free), bf16 h/p, f32 r. 359us.
// R9: csr_fill was 52us with 52MB WRITE_SIZE for a 3.2MB array (16x write amp:
// random 4B scatters, partial lines bounced across 8 non-coherent XCD L2s).
// Fix: dst-sliced fill, slice = blockIdx&7 -> under round-robin block->XCD
// dispatch each slice's 400KB esrc region stays in ONE XCD's L2 and lines
// collect ~16 writes before eviction. Each slice-group rescans dst (LLC-served).
// NOTE: harness delivers integer inputs as int32 -> edge_index is const int*.
// ---------------------------------------------------------------------------

#define HID 128
#define SCAN_CHUNK 1024
#define NSLICE 8
#define FILL_BLOCKS_PER_SLICE 104   // grid = 832 blocks, slice = blockIdx & 7

using short8 = __attribute__((ext_vector_type(8))) short;
using f32x4  = __attribute__((ext_vector_type(4))) float;

// ---- bf16 helpers (manual, RNE) -------------------------------------------

__device__ __forceinline__ unsigned short f32_to_bf16(float f)
{
    union { float f; unsigned int i; } c; c.f = f;
    const unsigned int x = c.i;
    const unsigned int r = x + 0x7fffu + ((x >> 16) & 1u);
    return (unsigned short)(r >> 16);
}

// ---- small utility --------------------------------------------------------

__global__ __launch_bounds__(256) void zero_i32_kernel(int* __restrict__ p, int n)
{
    int i = blockIdx.x * 256 + threadIdx.x;
    if (i < n) p[i] = 0;
}

// ---- CSR build ------------------------------------------------------------

__global__ __launch_bounds__(256) void deg_hist_kernel(
    const int* __restrict__ dst, int* __restrict__ deg, int E, int n)
{
    int e = blockIdx.x * 256 + threadIdx.x;
    if (e < E) {
        int d = dst[e];
        if (d >= 0 && d < n) atomicAdd(&deg[d], 1);
    }
}

__global__ __launch_bounds__(256) void block_sum_kernel(
    const int* __restrict__ deg, int* __restrict__ partials, int n)
{
    __shared__ int red[256];
    const int base = blockIdx.x * SCAN_CHUNK;
    const int t = threadIdx.x;
    int s = 0;
#pragma unroll
    for (int j = 0; j < 4; ++j) {
        const int idx = base + t * 4 + j;
        s += (idx < n) ? deg[idx] : 0;
    }
    red[t] = s;
    __syncthreads();
    for (int off = 128; off > 0; off >>= 1) {
        if (t < off) red[t] += red[t + off];
        __syncthreads();
    }
    if (t == 0) partials[blockIdx.x] = red[0];
}

__global__ __launch_bounds__(256) void scan_partials_kernel(
    int* __restrict__ partials, int nblk)
{
    __shared__ int buf[256];
    const int t = threadIdx.x;
    const int v = (t < nblk) ? partials[t] : 0;
    buf[t] = v;
    __syncthreads();
    for (int off = 1; off < 256; off <<= 1) {
        const int u = (t >= off) ? buf[t - off] : 0;
        __syncthreads();
        buf[t] += u;
        __syncthreads();
    }
    if (t < nblk) partials[t] = buf[t] - v;   // exclusive
}

__global__ __launch_bounds__(256) void scan_write_kernel(
    const int* __restrict__ deg, const int* __restrict__ partials,
    int* __restrict__ offs, int* __restrict__ cursor, int n, int E)
{
    __shared__ int buf[256];
    const int base = blockIdx.x * SCAN_CHUNK;
    const int t = threadIdx.x;
    int loc[4];
    int s = 0;
#pragma unroll
    for (int j = 0; j < 4; ++j) {
        const int idx = base + t * 4 + j;
        const int d = (idx < n) ? deg[idx] : 0;
        loc[j] = s;
        s += d;
    }
    buf[t] = s;
    __syncthreads();
    for (int off = 1; off < 256; off <<= 1) {
        const int u = (t >= off) ? buf[t - off] : 0;
        __syncthreads();
        buf[t] += u;
        __syncthreads();
    }
    const int tbase = partials[blockIdx.x] + ((t == 0) ? 0 : buf[t - 1]);
#pragma unroll
    for (int j = 0; j < 4; ++j) {
        const int idx = base + t * 4 + j;
        if (idx < n) {
            const int o = tbase + loc[j];
            offs[idx] = o;
            cursor[idx] = o;
        }
    }
    if (blockIdx.x == 0 && t == 0) offs[n] = E;
}

// dst-sliced CSR fill: slice = blockIdx & 7. Each slice-group scans all E
// edges but only scatters edges whose dst falls in its node range -> per-L2
// write locality (R9 fix for 16x write amplification).
__global__ __launch_bounds__(256) void csr_fill_sliced_kernel(
    const int* __restrict__ src, const int* __restrict__ dst,
    int* __restrict__ cursor, int* __restrict__ esrc, int E, int n)
{
    const int slice = blockIdx.x & (NSLICE - 1);
    const int nps   = (n + NSLICE - 1) / NSLICE;
    const int lo    = slice * nps;
    const int hi    = min(lo + nps, n);
    const int stride = FILL_BLOCKS_PER_SLICE * 256;
    int e = (blockIdx.x >> 3) * 256 + threadIdx.x;
    for (; e < E; e += stride) {
        const int d = dst[e];
        if (d >= lo && d < hi) {
            const int s = src[e];
            if ((unsigned)s < (unsigned)n) {
                const int p = atomicAdd(&cursor[d], 1);
                esrc[p] = s;
            }
        }
    }
}

// ---- W^T prep: wtc[c][k] = bf16( c<dout ? Wl[k][c] : Wr[k][c-dout] ) -------

__global__ __launch_bounds__(256) void prep_wt_kernel(
    const float* __restrict__ Wl, const float* __restrict__ Wr,
    unsigned short* __restrict__ wtc, int dout)
{
    const int idx = blockIdx.x * 256 + threadIdx.x;
    const int total = 2 * dout * HID;
    if (idx >= total) return;
    const int k = idx & (HID - 1);
    const int c = idx >> 7;
    const float v = (c < dout) ? Wl[(size_t)k * dout + c]
                               : Wr[(size_t)k * dout + (c - dout)];
    wtc[(size_t)c * HID + k] = f32_to_bf16(v);
}

// ---- MFMA dual GEMM: p = bf16(h@Wl), r = h@Wr + b (f32) -------------------
// 256 thr = 4 waves; wave owns 64 cols; B-frags resident in registers;
// grid-stride over 16-row slabs; no LDS, no barriers.

template <int DOUT, bool IN_F32>
__global__ __launch_bounds__(256) void sage_mfma_gemm(
    const void* __restrict__ hin,                 // [n][128] f32 or bf16
    const unsigned short* __restrict__ wtc,       // [2*DOUT][128] bf16
    const float* __restrict__ bias,
    unsigned short* __restrict__ p, float* __restrict__ r, int n)
{
    constexpr int TOTC = 2 * DOUT;
    constexpr int CPW  = TOTC / 64;   // col-tiles per wave: 4 (DOUT=128) or 2

    const int tx   = threadIdx.x;
    const int wv   = tx >> 6;
    const int lane = tx & 63;
    const int quad = lane >> 4;
    const int l15  = lane & 15;

    short8 B[CPW][4];
#pragma unroll
    for (int t = 0; t < CPW; ++t) {
        const int c = (wv * CPW + t) * 16 + l15;
#pragma unroll
        for (int q = 0; q < 4; ++q)
            B[t][q] = *(const short8*)(wtc + (size_t)c * HID + q * 32 + quad * 8);
    }

    const int slabs = (n + 15) >> 4;
    for (int slab = blockIdx.x; slab < slabs; slab += gridDim.x) {
        const int r0 = slab * 16;
        const int rr = min(r0 + l15, n - 1);

        short8 A[4];
        if (IN_F32) {
            const float* hf = (const float*)hin;
#pragma unroll
            for (int q = 0; q < 4; ++q) {
                const float* base = hf + (size_t)rr * HID + q * 32 + quad * 8;
                const float4 f0 = *(const float4*)base;
                const float4 f1 = *(const float4*)(base + 4);
                short8 a;
                a[0] = (short)f32_to_bf16(f0.x); a[1] = (short)f32_to_bf16(f0.y);
                a[2] = (short)f32_to_bf16(f0.z); a[3] = (short)f32_to_bf16(f0.w);
                a[4] = (short)f32_to_bf16(f1.x); a[5] = (short)f32_to_bf16(f1.y);
                a[6] = (short)f32_to_bf16(f1.z); a[7] = (short)f32_to_bf16(f1.w);
                A[q] = a;
            }
        } else {
            const unsigned short* hb = (const unsigned short*)hin;
#pragma unroll
            for (int q = 0; q < 4; ++q)
                A[q] = *(const short8*)(hb + (size_t)rr * HID + q * 32 + quad * 8);
        }

        f32x4 acc[CPW];
#pragma unroll
        for (int t = 0; t < CPW; ++t) acc[t] = (f32x4){0.f, 0.f, 0.f, 0.f};
#pragma unroll
        for (int q = 0; q < 4; ++q)
#pragma unroll
            for (int t = 0; t < CPW; ++t)
                acc[t] = __builtin_amdgcn_mfma_f32_16x16x32_bf16(A[q], B[t][q], acc[t], 0, 0, 0);

        // epilogue: C/D layout col=l15, row=quad*4+i
#pragma unroll
        for (int t = 0; t < CPW; ++t) {
            const int c0  = (wv * CPW + t) * 16;
            const int col = c0 + l15;
            if (c0 < DOUT) {
#pragma unroll
                for (int i = 0; i < 4; ++i) {
                    const int row = r0 + quad * 4 + i;
                    if (row < n) p[(size_t)row * DOUT + col] = f32_to_bf16(acc[t][i]);
                }
            } else {
                const float bv = bias[col - DOUT];
#pragma unroll
                for (int i = 0; i < 4; ++i) {
                    const int row = r0 + quad * 4 + i;
                    if (row < n) r[(size_t)row * DOUT + (col - DOUT)] = acc[t][i] + bv;
                }
            }
        }
    }
}

// ---- Post-aggregation: out = act( mean(p_bf16[nbrs]) + r ) ----------------
// One wave per dst node; predicated x8 unroll (8 gathers in flight).

template <int DOUT, bool RELU, bool OUTBF16>
__global__ __launch_bounds__(256) void sage_post_aggregate(
    const unsigned short* __restrict__ p, const float* __restrict__ r,
    const int* __restrict__ offs, const int* __restrict__ esrc,
    void* __restrict__ out, int n)
{
    const int wid  = threadIdx.x >> 6;
    const int lane = threadIdx.x & 63;
    const int node = blockIdx.x * 4 + wid;
    if (node >= n) return;
    const int beg = offs[node];
    const int end = offs[node + 1];
    const float inv = 1.0f / fmaxf((float)(end - beg), 1.0f);

    if constexpr (DOUT == 128) {
        float ax[8], ay[8];
#pragma unroll
        for (int j = 0; j < 8; ++j) { ax[j] = 0.f; ay[j] = 0.f; }
        for (int e = beg; e < end; e += 8) {
#pragma unroll
            for (int j = 0; j < 8; ++j) {
                const int idx = e + j;
                const int ee  = min(idx, end - 1);
                const float w = (idx < end) ? 1.0f : 0.0f;
                const int s   = esrc[ee];
                const unsigned int v = *(const unsigned int*)(&p[(size_t)s * DOUT + lane * 2]);
                float fx, fy;
                { union { unsigned int i; float f; } c; c.i = v << 16;          fx = c.f; }
                { union { unsigned int i; float f; } c; c.i = v & 0xffff0000u;  fy = c.f; }
                ax[j] = fmaf(w, fx, ax[j]);
                ay[j] = fmaf(w, fy, ay[j]);
            }
        }
        float sx = ((ax[0] + ax[1]) + (ax[2] + ax[3])) + ((ax[4] + ax[5]) + (ax[6] + ax[7]));
        float sy = ((ay[0] + ay[1]) + (ay[2] + ay[3])) + ((ay[4] + ay[5]) + (ay[6] + ay[7]));
        const float2 rv = *(const float2*)(&r[(size_t)node * DOUT + lane * 2]);
        float ox = sx * inv + rv.x;
        float oy = sy * inv + rv.y;
        if (RELU) { ox = fmaxf(ox, 0.f); oy = fmaxf(oy, 0.f); }
        if (OUTBF16) {
            const unsigned int pk = ((unsigned int)f32_to_bf16(oy) << 16) | (unsigned int)f32_to_bf16(ox);
            ((unsigned int*)out)[(size_t)node * (DOUT / 2) + lane] = pk;
        } else {
            float2 o; o.x = ox; o.y = oy;
            *(float2*)((float*)out + (size_t)node * DOUT + lane * 2) = o;
        }
    } else {
        float a[8];
#pragma unroll
        for (int j = 0; j < 8; ++j) a[j] = 0.f;
        for (int e = beg; e < end; e += 8) {
#pragma unroll
            for (int j = 0; j < 8; ++j) {
                const int idx = e + j;
                const int ee  = min(idx, end - 1);
                const float w = (idx < end) ? 1.0f : 0.0f;
                const int s   = esrc[ee];
                const unsigned short u = p[(size_t)s * DOUT + lane];
                union { unsigned int i; float f; } c; c.i = ((unsigned int)u) << 16;
                a[j] = fmaf(w, c.f, a[j]);
            }
        }
        float sa = ((a[0] + a[1]) + (a[2] + a[3])) + ((a[4] + a[5]) + (a[6] + a[7]));
        float o = sa * inv + r[(size_t)node * DOUT + lane];
        if (RELU) o = fmaxf(o, 0.f);
        ((float*)out)[(size_t)node * DOUT + lane] = o;
    }
}

// ---------------------------------------------------------------------------

static inline size_t align_up(size_t v, size_t a) { return (v + a - 1) & ~(a - 1); }

extern "C" void kernel_launch(void* const* d_in, const int* in_sizes, int n_in,
                              void* d_out, int out_size, void* d_ws, size_t ws_size,
                              hipStream_t stream)
{
    const float* x   = (const float*)d_in[0];
    const int*   ei  = (const int*)d_in[1];      // int32! (harness converts int64)
    const float* wl0 = (const float*)d_in[2];
    const float* b0  = (const float*)d_in[3];
    const float* wr0 = (const float*)d_in[4];
    const float* wl1 = (const float*)d_in[5];
    const float* b1  = (const float*)d_in[6];
    const float* wr1 = (const float*)d_in[7];
    const float* wl2 = (const float*)d_in[8];
    const float* b2  = (const float*)d_in[9];
    const float* wr2 = (const float*)d_in[10];
    float*       out = (float*)d_out;

    const int N = in_sizes[0] / HID;   // 50000
    const int E = in_sizes[1] / 2;     // 800000
    const int* src = ei;
    const int* dst = ei + E;

    // Workspace carve-up (~55 MB)
    char*  ws  = (char*)d_ws;
    size_t off = 0;
    int* offs     = (int*)(ws + off); off = align_up(off + (size_t)(N + 1) * 4, 256);
    int* cursor   = (int*)(ws + off); off = align_up(off + (size_t)N * 4, 256);
    int* deg      = (int*)(ws + off); off = align_up(off + (size_t)N * 4, 256);
    int* partials = (int*)(ws + off); off = align_up(off + 256 * 4, 256);
    int* esrc     = (int*)(ws + off); off = align_up(off + (size_t)E * 4, 256);
    unsigned short* pbuf = (unsigned short*)(ws + off); off = align_up(off + (size_t)N * HID * 2, 256);
    float* rbuf   = (float*)(ws + off); off = align_up(off + (size_t)N * HID * 4, 256);
    unsigned short* hbf = (unsigned short*)(ws + off); off = align_up(off + (size_t)N * HID * 2, 256);
    unsigned short* wt0 = (unsigned short*)(ws + off); off = align_up(off + (size_t)2 * HID * HID * 2, 256);
    unsigned short* wt1 = (unsigned short*)(ws + off); off = align_up(off + (size_t)2 * HID * HID * 2, 256);
    unsigned short* wt2 = (unsigned short*)(ws + off); off = align_up(off + (size_t)HID * HID * 2, 256);
    (void)ws_size; (void)n_in; (void)out_size;

    const int nScanBlk = (N + SCAN_CHUNK - 1) / SCAN_CHUNK;   // 49

    // --- CSR build (reused by all 3 layers) ---
    zero_i32_kernel<<<(N + 255) / 256, 256, 0, stream>>>(deg, N);
    deg_hist_kernel<<<(E + 255) / 256, 256, 0, stream>>>(dst, deg, E, N);
    block_sum_kernel<<<nScanBlk, 256, 0, stream>>>(deg, partials, N);
    scan_partials_kernel<<<1, 256, 0, stream>>>(partials, nScanBlk);
    scan_write_kernel<<<nScanBlk, 256, 0, stream>>>(deg, partials, offs, cursor, N, E);
    csr_fill_sliced_kernel<<<NSLICE * FILL_BLOCKS_PER_SLICE, 256, 0, stream>>>(
        src, dst, cursor, esrc, E, N);

    // --- W^T preps (bf16) ---
    prep_wt_kernel<<<(2 * HID * HID + 255) / 256, 256, 0, stream>>>(wl0, wr0, wt0, HID);
    prep_wt_kernel<<<(2 * HID * HID + 255) / 256, 256, 0, stream>>>(wl1, wr1, wt1, HID);
    prep_wt_kernel<<<(HID * HID + 255) / 256, 256, 0, stream>>>(wl2, wr2, wt2, 64);

    const int aggGrid  = (N + 3) / 4;
    const int gemmGrid = 1024;   // grid-stride over 3125 slabs

    // Layer 0: x (f32) -> p/r -> hbf (bf16, ReLU)
    sage_mfma_gemm<128, true><<<gemmGrid, 256, 0, stream>>>(x, wt0, b0, pbuf, rbuf, N);
    sage_post_aggregate<128, true, true><<<aggGrid, 256, 0, stream>>>(pbuf, rbuf, offs, esrc, hbf, N);

    // Layer 1: hbf -> p/r -> hbf (bf16, ReLU)
    sage_mfma_gemm<128, false><<<gemmGrid, 256, 0, stream>>>(hbf, wt1, b1, pbuf, rbuf, N);
    sage_post_aggregate<128, true, true><<<aggGrid, 256, 0, stream>>>(pbuf, rbuf, offs, esrc, hbf, N);

    // Layer 2: hbf -> p/r -> out (f32, no ReLU)
    sage_mfma_gemm<64, false><<<gemmGrid, 256, 0, stream>>>(hbf, wt2, b2, pbuf, rbuf, N);
    sage_post_aggregate<64, false, false><<<aggGrid, 256, 0, stream>>>(pbuf, rbuf, offs, esrc, out, N);
}